// Round 11
// baseline (462.857 us; speedup 1.0000x reference)
//
#include <hip/hip_runtime.h>
#include <hip/hip_fp16.h>
#include <math.h>

#define N_NODES 100000
#define N_EDGES 1600000
#define SLOPE 0.2f

// ---- counting-sort CSR build parameters ----
#define BSHIFT 8                      // 256 nodes per bucket
#define NB 391                        // ceil(100000/256)
#define CHUNK 8192                    // edges per partition block

typedef _Float16 f16x8 __attribute__((ext_vector_type(8)));
typedef float f32x4 __attribute__((ext_vector_type(4)));
typedef float f32x8v __attribute__((ext_vector_type(8)));

// ----------------- CSR build: two-level LDS counting sort -----------------
// partA1: per-(chunk-block,bucket) counts + bucket totals. Also performs the
// weight convert (fp32 -> fp16 transposed+pre-swizzled) in its first 192
// blocks' early lanes — saves a dispatch, zero interaction with the counts.
__global__ __launch_bounds__(256) void partA1(
    const int* __restrict__ ei, int* __restrict__ bucket_count,
    int* __restrict__ blkcnt,  // [NB][nblk]
    int E, int n, int nblk,
    const float* __restrict__ W1, const float* __restrict__ W2,
    const float* __restrict__ W3, __half* __restrict__ Wt1,
    __half* __restrict__ Wt2, __half* __restrict__ Wt3) {
  // ---- fused weight convert: Wt[col][ ((k>>3)^(col&15))*8 + (k&7) ] ----
  {
    int idx = blockIdx.x * 256 + threadIdx.x;
    if (idx < 3 * 16384) {
      int mat = idx >> 14;
      int r = idx & 16383;
      int k = r >> 7, col = r & 127;
      const float* W = (mat == 0) ? W1 : (mat == 1) ? W2 : W3;
      __half* Wt = (mat == 0) ? Wt1 : (mat == 1) ? Wt2 : Wt3;
      int sw = (((k >> 3) ^ (col & 15)) << 3) | (k & 7);
      Wt[col * 128 + sw] = __float2half(W[k * 128 + col]);
    }
  }
  __shared__ int cnt[NB];
  for (int i = threadIdx.x; i < NB; i += 256) cnt[i] = 0;
  __syncthreads();
  int b = blockIdx.x;
  int base = b * CHUNK;
  int total = E + n;
  int lim = min(base + CHUNK, total);
  for (int e = base + threadIdx.x; e < lim; e += 256) {
    int d = (e < E) ? ei[E + e] : (e - E);
    atomicAdd(&cnt[d >> BSHIFT], 1);
  }
  __syncthreads();
  for (int i = threadIdx.x; i < NB; i += 256) {
    int c = cnt[i];
    blkcnt[i * nblk + b] = c;
    if (c) atomicAdd(&bucket_count[i], c);
  }
}

// scan_all: merges the old scan_nb + scan_blk. Each of the NB blocks
// redundantly scans the 391 bucket totals (trivial), block 0 publishes
// bucket_base; then each block scans its bucket's per-chunk counts.
__global__ __launch_bounds__(512) void scan_all(
    const int* __restrict__ bucket_count, const int* __restrict__ blkcnt,
    int* __restrict__ bucket_base, int* __restrict__ blk_base, int nblk) {
  __shared__ int lds[512];
  __shared__ int base_sh;
  int t = threadIdx.x;
  int bid = blockIdx.x;
  // phase 1: scan bucket totals
  int v = (t < NB) ? bucket_count[t] : 0;
  int x = v;
  lds[t] = x;
  __syncthreads();
  for (int off = 1; off < 512; off <<= 1) {
    int y = (t >= off) ? lds[t - off] : 0;
    __syncthreads();
    x += y;
    lds[t] = x;
    __syncthreads();
  }
  if (bid == 0 && t <= NB) bucket_base[t] = x - v;
  if (t == bid) base_sh = x - v;
  __syncthreads();
  int base_i = base_sh;
  // phase 2: scan this bucket's per-chunk counts
  int w = (t < nblk) ? blkcnt[bid * nblk + t] : 0;
  int x2 = w;
  lds[t] = x2;
  __syncthreads();
  for (int off = 1; off < 512; off <<= 1) {
    int y = (t >= off) ? lds[t - off] : 0;
    __syncthreads();
    x2 += y;
    lds[t] = x2;
    __syncthreads();
  }
  if (t < nblk) blk_base[bid * nblk + t] = base_i + (x2 - w);
}

__global__ __launch_bounds__(256) void partA2(const int* __restrict__ ei,
                                              const int* __restrict__ blk_base,
                                              unsigned* __restrict__ part,
                                              int E, int n, int nblk) {
  __shared__ int res[NB];
  int b = blockIdx.x;
  for (int i = threadIdx.x; i < NB; i += 256) res[i] = blk_base[i * nblk + b];
  __syncthreads();
  int base = b * CHUNK;
  int total = E + n;
  int lim = min(base + CHUNK, total);
  for (int e = base + threadIdx.x; e < lim; e += 256) {
    int s, d;
    if (e < E) { s = ei[e]; d = ei[E + e]; } else { s = d = e - E; }
    int bk = d >> BSHIFT;
    int pos = atomicAdd(&res[bk], 1);  // LDS atomic; res holds global cursor
    part[pos] = ((unsigned)s << BSHIFT) | (unsigned)(d & 255);
  }
}

__global__ __launch_bounds__(256) void passB(const unsigned* __restrict__ part,
                                             const int* __restrict__ bucket_base,
                                             int* __restrict__ row_start,
                                             int* __restrict__ edge_src, int n) {
  __shared__ int cnt[256];
  __shared__ int sc[256];
  __shared__ int loff[256];
  int b = blockIdx.x;
  int t = threadIdx.x;
  int node0 = b << BSHIFT;
  int bstart = bucket_base[b], bend = bucket_base[b + 1];
  cnt[t] = 0;
  __syncthreads();
  for (int i = bstart + t; i < bend; i += 256)
    atomicAdd(&cnt[part[i] & 255], 1);
  __syncthreads();
  int v = cnt[t];
  int x = v;
  sc[t] = x;
  __syncthreads();
  for (int off = 1; off < 256; off <<= 1) {
    int y = (t >= off) ? sc[t - off] : 0;
    __syncthreads();
    x += y;
    sc[t] = x;
    __syncthreads();
  }
  int excl = x - v;
  loff[t] = excl;
  int node = node0 + t;
  if (node < n) row_start[node] = bstart + excl;
  if (b == NB - 1 && t == 0) row_start[n] = bucket_base[NB];
  __syncthreads();
  for (int i = bstart + t; i < bend; i += 256) {
    unsigned p = part[i];
    int dl = p & 255;
    int pos = bstart + atomicAdd(&loff[dl], 1);
    edge_src[pos] = (int)(p >> BSHIFT);
  }
}

// ---- MFMA fp16 GEMM [n,128]x[128,128] + fused attention dots ----
// 128 rows/block (4 waves x two 16-row tiles); each B fragment ds_read feeds
// TWO MFMAs. __launch_bounds__(256,2): VGPR cap 256 — the (256,3) cap of
// ~170 was at/over the ~170-reg working set (acc 64 + A 32 + dots 48 + addr)
// and risked scratch spills. A direct-from-global; B linear 32KB copy
// (pre-swizzled); Y via LDS transpose, 4 coalesced dwordx4/lane.
template <int H, typename InT>
__global__ __launch_bounds__(256, 2) void gemm_att_mfma(
    const InT* __restrict__ X, const __half* __restrict__ Wt,  // pre-swizzled
    const float* __restrict__ att_src, const float* __restrict__ att_dst,
    __half* __restrict__ Y, float* __restrict__ a_s, float* __restrict__ a_d,
    int n) {
  __shared__ _Float16 B_lds[17408];  // 34.8 KB: [0,16384)=B; full=Y staging
  int t = threadIdx.x;
  int r0 = blockIdx.x * 128;
  int wv = t >> 6, lane = t & 63, quad = lane >> 4, l15 = lane & 15;

  // stage B: linear 32KB copy (Wt already swizzled)
  {
    const __half* wp = Wt + t * 64;
#pragma unroll
    for (int i = 0; i < 8; i++)
      *(float4*)&B_lds[t * 64 + i * 8] = *(const float4*)(wp + i * 8);
  }

  // A fragments for two 16-row tiles: rows r0+wv*32+mt*16+l15,
  // halves [kb*32+quad*8 .. +8) (16x16x32 A layout, m89/m91).
  f16x8 a[2][4];
#pragma unroll
  for (int mt = 0; mt < 2; mt++) {
    int arow = r0 + wv * 32 + mt * 16 + l15;
    bool inb = arow < n;
    if constexpr (sizeof(InT) == 4) {
      const float* xp = (const float*)X + (size_t)arow * 128 + quad * 8;
#pragma unroll
      for (int kb = 0; kb < 4; kb++) {
        float4 v0, v1;
        if (inb) {
          v0 = *(const float4*)(xp + kb * 32);
          v1 = *(const float4*)(xp + kb * 32 + 4);
        } else {
          v0 = make_float4(0.f, 0.f, 0.f, 0.f);
          v1 = v0;
        }
        f32x8v f = {v0.x, v0.y, v0.z, v0.w, v1.x, v1.y, v1.z, v1.w};
        a[mt][kb] = __builtin_convertvector(f, f16x8);
      }
    } else {
      const __half* xp = (const __half*)X + (size_t)arow * 128 + quad * 8;
      f16x8 z = {};
#pragma unroll
      for (int kb = 0; kb < 4; kb++) {
        if (inb) a[mt][kb] = *(const f16x8*)(xp + kb * 32);
        else a[mt][kb] = z;
      }
    }
  }
  __syncthreads();

  f32x4 acc[2][8];
#pragma unroll
  for (int mt = 0; mt < 2; mt++)
#pragma unroll
    for (int ct = 0; ct < 8; ct++) acc[mt][ct] = (f32x4){0.f, 0.f, 0.f, 0.f};

#pragma unroll
  for (int kb = 0; kb < 4; kb++) {
#pragma unroll
    for (int ct = 0; ct < 8; ct++) {
      f16x8 b = *(const f16x8*)(
          &B_lds[(ct * 16 + l15) * 128 + (((kb * 4 + quad) ^ l15) * 8)]);
      acc[0][ct] =
          __builtin_amdgcn_mfma_f32_16x16x32_f16(a[0][kb], b, acc[0][ct], 0, 0, 0);
      acc[1][ct] =
          __builtin_amdgcn_mfma_f32_16x16x32_f16(a[1][kb], b, acc[1][ct], 0, 0, 0);
    }
  }

  // fused attention dots (register-only), per 16-row tile
  float avs[8], avd[8];
#pragma unroll
  for (int ct = 0; ct < 8; ct++) {
    avs[ct] = att_src[ct * 16 + l15];
    avd[ct] = att_dst[ct * 16 + l15];
  }
#pragma unroll
  for (int mt = 0; mt < 2; mt++) {
    int rbase = r0 + wv * 32 + mt * 16 + quad * 4;
    if constexpr (H == 4) {
      float ps[4][4], pd_[4][4];  // [head][reg]
#pragma unroll
      for (int hd = 0; hd < 4; hd++)
#pragma unroll
        for (int reg = 0; reg < 4; reg++) { ps[hd][reg] = 0.f; pd_[hd][reg] = 0.f; }
#pragma unroll
      for (int ct = 0; ct < 8; ct++) {
        int hd = ct >> 1;
#pragma unroll
        for (int reg = 0; reg < 4; reg++) {
          ps[hd][reg] = fmaf(acc[mt][ct][reg], avs[ct], ps[hd][reg]);
          pd_[hd][reg] = fmaf(acc[mt][ct][reg], avd[ct], pd_[hd][reg]);
        }
      }
#pragma unroll
      for (int off = 1; off <= 8; off <<= 1)
#pragma unroll
        for (int hd = 0; hd < 4; hd++)
#pragma unroll
          for (int reg = 0; reg < 4; reg++) {
            ps[hd][reg] += __shfl_xor(ps[hd][reg], off, 64);
            pd_[hd][reg] += __shfl_xor(pd_[hd][reg], off, 64);
          }
#pragma unroll
      for (int hd = 0; hd < 4; hd++)
        if (l15 == hd) {
#pragma unroll
          for (int reg = 0; reg < 4; reg++) {
            int row = rbase + reg;
            if (row < n) {
              a_s[row * 4 + hd] = ps[hd][reg];
              a_d[row * 4 + hd] = pd_[hd][reg];
            }
          }
        }
    } else {
      float ps[4] = {}, pd_[4] = {};
#pragma unroll
      for (int ct = 0; ct < 8; ct++)
#pragma unroll
        for (int reg = 0; reg < 4; reg++) {
          ps[reg] = fmaf(acc[mt][ct][reg], avs[ct], ps[reg]);
          pd_[reg] = fmaf(acc[mt][ct][reg], avd[ct], pd_[reg]);
        }
#pragma unroll
      for (int off = 1; off <= 8; off <<= 1)
#pragma unroll
        for (int reg = 0; reg < 4; reg++) {
          ps[reg] += __shfl_xor(ps[reg], off, 64);
          pd_[reg] += __shfl_xor(pd_[reg], off, 64);
        }
      if (l15 == 0) {
#pragma unroll
        for (int reg = 0; reg < 4; reg++) {
          int row = rbase + reg;
          if (row < n) { a_s[row] = ps[reg]; a_d[row] = pd_[reg]; }
        }
      }
    }
  }

  // ---- Y-store via LDS transpose: all waves done reading B_lds first ----
  __syncthreads();
  {
    const int LW = 136;  // padded row (halves): 272 B, 16-B aligned
#pragma unroll
    for (int mt = 0; mt < 2; mt++) {
      _Float16* wreg = &B_lds[(wv * 32 + mt * 16) * LW];  // max idx 17407
#pragma unroll
      for (int reg = 0; reg < 4; reg++) {
        int rl = quad * 4 + reg;
#pragma unroll
        for (int ct = 0; ct < 8; ct++)
          wreg[rl * LW + ct * 16 + l15] = (_Float16)acc[mt][ct][reg];
      }
      // wave-local: lgkmcnt ordering covers write->read within the wave
#pragma unroll
      for (int j = 0; j < 4; j++) {
        int rl = j * 4 + quad;
        int seg = l15;
        int rowg = r0 + wv * 32 + mt * 16 + rl;
        if (rowg < n) {
          float4 v = *(const float4*)&wreg[rl * LW + seg * 8];
          *(float4*)(Y + (size_t)rowg * 128 + seg * 8) = v;
        }
      }
    }
  }
}

// ----------------- softmax + aggregation, one wave per dst node ----------
// At its random-gather roofline (240 MB @ ~3.5 TB/s across 6 variants);
// structure frozen. Pass 1: constant-shift softmax exp(e-40), fast-rcp.
// Pass 2: 16 lanes x 8 dims x 4 groups, v_fma_mix_f32 MACs.
template <int H, bool DO_ELU, typename OutT>
__global__ __launch_bounds__(256) void agg_kernel(
    const __half* __restrict__ h, const float* __restrict__ a_s,
    const float* __restrict__ a_d, const int* __restrict__ row_start,
    const int* __restrict__ edge_src, const float* __restrict__ bias,
    OutT* __restrict__ out, int n) {
  const int C = 128 / H;
  __shared__ float w_lds[4][H * 66];
  __shared__ int sn_lds[4][64];
  int wslot = threadIdx.x >> 6;
  int wid = (blockIdx.x * blockDim.x + threadIdx.x) >> 6;
  int lane = threadIdx.x & 63;
  if (wid >= n) return;
  int start = row_start[wid], end = row_start[wid + 1];
  int deg = end - start;

  float adv[H];
#pragma unroll
  for (int hh = 0; hh < H; hh++) adv[hh] = a_d[wid * H + hh];

  if (deg <= 64) {
    // ---- pass 1 ----
    bool valid = lane < deg;
    int sn = valid ? edge_src[start + lane] : 0;
    float e[H];
    if (valid) {
      if constexpr (H == 4) {
        float4 asv = *(const float4*)(a_s + (size_t)sn * 4);
        float t0 = asv.x + adv[0];
        float t1 = asv.y + adv[1];
        float t2 = asv.z + adv[2];
        float t3 = asv.w + adv[3];
        e[0] = t0 >= 0.f ? t0 : SLOPE * t0;
        e[1] = t1 >= 0.f ? t1 : SLOPE * t1;
        e[2] = t2 >= 0.f ? t2 : SLOPE * t2;
        e[3] = t3 >= 0.f ? t3 : SLOPE * t3;
      } else {
        float tt = a_s[sn] + adv[0];
        e[0] = tt >= 0.f ? tt : SLOPE * tt;
      }
    } else {
#pragma unroll
      for (int hh = 0; hh < H; hh++) e[hh] = -1e30f;
    }
    bool small = (deg <= 32);
    float w[H], s[H];
#pragma unroll
    for (int hh = 0; hh < H; hh++) {
      w[hh] = valid ? __expf(e[hh] - 40.f) : 0.f;
      s[hh] = w[hh];
    }
#pragma unroll
    for (int off = 1; off <= 16; off <<= 1)
#pragma unroll
      for (int hh = 0; hh < H; hh++) s[hh] += __shfl_xor(s[hh], off, 64);
    if (!small)
#pragma unroll
      for (int hh = 0; hh < H; hh++) s[hh] += __shfl_xor(s[hh], 32, 64);
    sn_lds[wslot][lane] = sn << 8;  // byte offset into h (256 B rows)
#pragma unroll
    for (int hh = 0; hh < H; hh++)
      w_lds[wslot][hh * 66 + lane] =
          valid ? w[hh] * __builtin_amdgcn_rcpf(s[hh]) : 0.f;
    __builtin_amdgcn_wave_barrier();

    // ---- pass 2: 16 lanes x 8 dims, 4 groups, 2 edges/lane in flight ----
    int g = lane >> 4, l = lane & 15;
    int d0 = l * 8;
    const char* hb = (const char*)h + l * 16;  // lane's 8-half slice base
    int headBase = (H == 4) ? (l >> 2) * 66 : 0;
    float acc[8] = {};
    int degp8 = (deg + 7) & ~7;  // pad slots have w=0, snoff=0 (safe row)
    for (int eidx = 0; eidx < degp8; eidx += 8) {
#pragma unroll
      for (int jj = 0; jj < 2; jj++) {
        int ei2 = eidx + jj * 4 + g;
        int boff = sn_lds[wslot][ei2];
        float wv = w_lds[wslot][headBase + ei2];
        f16x8 hv = *(const f16x8*)(hb + (unsigned)boff);
#pragma unroll
        for (int k = 0; k < 8; k++)
          acc[k] = fmaf((float)hv[k], wv, acc[k]);  // v_fma_mix_f32
      }
    }
    float o[8];
#pragma unroll
    for (int k = 0; k < 8; k++) {
      float v = acc[k];
      v += __shfl_xor(v, 16, 64);
      v += __shfl_xor(v, 32, 64);
      o[k] = v;
    }
    if (lane < 16) {
      float4 bv0 = *(const float4*)(bias + d0);
      float4 bv1 = *(const float4*)(bias + d0 + 4);
      o[0] += bv0.x; o[1] += bv0.y; o[2] += bv0.z; o[3] += bv0.w;
      o[4] += bv1.x; o[5] += bv1.y; o[6] += bv1.z; o[7] += bv1.w;
      if (DO_ELU) {
#pragma unroll
        for (int k = 0; k < 8; k++)
          o[k] = (o[k] > 0.f) ? o[k] : __expf(o[k]) - 1.f;
      }
      if constexpr (sizeof(OutT) == 2) {
        union { float4 f4; __half2 h2[4]; } uo;
        uo.h2[0] = __floats2half2_rn(o[0], o[1]);
        uo.h2[1] = __floats2half2_rn(o[2], o[3]);
        uo.h2[2] = __floats2half2_rn(o[4], o[5]);
        uo.h2[3] = __floats2half2_rn(o[6], o[7]);
        *(float4*)((__half*)out + (size_t)wid * 128 + d0) = uo.f4;
      } else {
        float4 ov0 = {o[0], o[1], o[2], o[3]};
        float4 ov1 = {o[4], o[5], o[6], o[7]};
        *(float4*)((float*)out + (size_t)wid * 128 + d0) = ov0;
        *(float4*)((float*)out + (size_t)wid * 128 + d0 + 4) = ov1;
      }
    }
    return;
  }

  // ---- generic fallback (deg > 64) — correctness only, ~never taken ----
  {
    const int G = C / 2;
    int head = lane / G;
    float m[H], s[H];
#pragma unroll
    for (int hh = 0; hh < H; hh++) { m[hh] = -1e30f; s[hh] = 0.f; }
    for (int idx = start + lane; idx < end; idx += 64) {
      int sn = edge_src[idx];
#pragma unroll
      for (int hh = 0; hh < H; hh++) {
        float e = a_s[sn * H + hh] + adv[hh];
        e = (e >= 0.f) ? e : SLOPE * e;
        float mn = fmaxf(m[hh], e);
        s[hh] = s[hh] * __expf(m[hh] - mn) + __expf(e - mn);
        m[hh] = mn;
      }
    }
    for (int off = 1; off < 64; off <<= 1) {
#pragma unroll
      for (int hh = 0; hh < H; hh++) {
        float mo = __shfl_xor(m[hh], off, 64);
        float so = __shfl_xor(s[hh], off, 64);
        float mn = fmaxf(m[hh], mo);
        s[hh] = s[hh] * __expf(m[hh] - mn) + so * __expf(mo - mn);
        m[hh] = mn;
      }
    }
    int d0 = lane * 2;
    float mh = m[head];
    float rsh = 1.f / s[head];
    float adh = adv[head];
    float acc0 = 0.f, acc1 = 0.f;
    for (int idx = start; idx < end; idx++) {
      int sn = edge_src[idx];
      float e = a_s[sn * H + head] + adh;
      e = (e >= 0.f) ? e : SLOPE * e;
      float w = __expf(e - mh) * rsh;
      float2 hv = __half22float2(*(const __half2*)(h + (size_t)sn * 128 + d0));
      acc0 += w * hv.x;
      acc1 += w * hv.y;
    }
    float o0 = acc0 + bias[d0];
    float o1 = acc1 + bias[d0 + 1];
    if (DO_ELU) {
      o0 = (o0 > 0.f) ? o0 : __expf(o0) - 1.f;
      o1 = (o1 > 0.f) ? o1 : __expf(o1) - 1.f;
    }
    out[(size_t)wid * 128 + d0] = (OutT)o0;
    out[(size_t)wid * 128 + d0 + 1] = (OutT)o1;
  }
}

extern "C" void kernel_launch(void* const* d_in, const int* in_sizes, int n_in,
                              void* d_out, int out_size, void* d_ws,
                              size_t ws_size, hipStream_t stream) {
  const float* x = (const float*)d_in[0];
  const int* ei = (const int*)d_in[1];
  const float* W1 = (const float*)d_in[2];
  const float* as1 = (const float*)d_in[3];
  const float* ad1 = (const float*)d_in[4];
  const float* b1 = (const float*)d_in[5];
  const float* W2 = (const float*)d_in[6];
  const float* as2 = (const float*)d_in[7];
  const float* ad2 = (const float*)d_in[8];
  const float* b2 = (const float*)d_in[9];
  const float* W3 = (const float*)d_in[10];
  const float* as3 = (const float*)d_in[11];
  const float* ad3 = (const float*)d_in[12];
  const float* b3 = (const float*)d_in[13];
  float* out = (float*)d_out;

  const int n = N_NODES, E = N_EDGES, total = E + n;
  const int nblkA = (total + CHUNK - 1) / CHUNK;  // 208

  char* ws = (char*)d_ws;
  size_t off = 0;
  auto alloc = [&](size_t bytes) -> char* {
    char* p = ws + off;
    off = (off + bytes + 255) & ~(size_t)255;
    return p;
  };
  __half* hbuf = (__half*)alloc(sizeof(__half) * (size_t)n * 128);  // 25.6 MB
  float* a_s = (float*)alloc(sizeof(float) * n * 4);
  float* a_d = (float*)alloc(sizeof(float) * n * 4);
  unsigned* part = (unsigned*)alloc(sizeof(unsigned) * total);  // 6.8 MB
  int* edge_src = (int*)alloc(sizeof(int) * total);             // 6.8 MB
  int* row_start = (int*)alloc(sizeof(int) * (n + 1));
  int* bucket_count = (int*)alloc(sizeof(int) * (NB + 1));
  int* bucket_base = (int*)alloc(sizeof(int) * (NB + 1));
  int* blkcnt = (int*)alloc(sizeof(int) * NB * nblkA);   // 325 KB
  int* blk_base = (int*)alloc(sizeof(int) * NB * nblkA); // 325 KB
  __half* Wt1 = (__half*)alloc(sizeof(__half) * 16384);
  __half* Wt2 = (__half*)alloc(sizeof(__half) * 16384);
  __half* Wt3 = (__half*)alloc(sizeof(__half) * 16384);
  __half* hbuf2 = (__half*)alloc(sizeof(__half) * (size_t)n * 128);  // 25.6 MB
  bool fp16mid = (off <= ws_size);

  hipMemsetAsync(bucket_count, 0, sizeof(int) * (NB + 1), stream);

  // CSR build (+fused weight convert in partA1)
  partA1<<<nblkA, 256, 0, stream>>>(ei, bucket_count, blkcnt, E, n, nblkA,
                                    W1, W2, W3, Wt1, Wt2, Wt3);
  scan_all<<<NB, 512, 0, stream>>>(bucket_count, blkcnt, bucket_base,
                                   blk_base, nblkA);
  partA2<<<nblkA, 256, 0, stream>>>(ei, blk_base, part, E, n, nblkA);
  passB<<<NB, 256, 0, stream>>>(part, bucket_base, row_start, edge_src, n);

  int agg_blocks = (n + 3) / 4;         // one wave per node, 4 waves/block
  int gemm_blocks = (n + 127) / 128;    // 128 rows per block

  if (fp16mid) {
    // layer 1: x -> hbuf(+dots) -> hbuf2 fp16 (ELU)
    gemm_att_mfma<4, float><<<gemm_blocks, 256, 0, stream>>>(
        x, Wt1, as1, ad1, hbuf, a_s, a_d, n);
    agg_kernel<4, true, __half><<<agg_blocks, 256, 0, stream>>>(
        hbuf, a_s, a_d, row_start, edge_src, b1, hbuf2, n);

    // layer 2: hbuf2 -> hbuf(+dots) -> hbuf2 fp16 (ELU)
    gemm_att_mfma<4, __half><<<gemm_blocks, 256, 0, stream>>>(
        hbuf2, Wt2, as2, ad2, hbuf, a_s, a_d, n);
    agg_kernel<4, true, __half><<<agg_blocks, 256, 0, stream>>>(
        hbuf, a_s, a_d, row_start, edge_src, b2, hbuf2, n);

    // layer 3: hbuf2 -> hbuf(+dots) -> out fp32 (no ELU), heads=1
    gemm_att_mfma<1, __half><<<gemm_blocks, 256, 0, stream>>>(
        hbuf2, Wt3, as3, ad3, hbuf, a_s, a_d, n);
    agg_kernel<1, false, float><<<agg_blocks, 256, 0, stream>>>(
        hbuf, a_s, a_d, row_start, edge_src, b3, out, n);
  } else {
    // fp32 intermediate fallback (workspace-tight path)
    gemm_att_mfma<4, float><<<gemm_blocks, 256, 0, stream>>>(
        x, Wt1, as1, ad1, hbuf, a_s, a_d, n);
    agg_kernel<4, true, float><<<agg_blocks, 256, 0, stream>>>(
        hbuf, a_s, a_d, row_start, edge_src, b1, out, n);

    gemm_att_mfma<4, float><<<gemm_blocks, 256, 0, stream>>>(
        out, Wt2, as2, ad2, hbuf, a_s, a_d, n);
    agg_kernel<4, true, float><<<agg_blocks, 256, 0, stream>>>(
        hbuf, a_s, a_d, row_start, edge_src, b2, out, n);

    gemm_att_mfma<1, float><<<gemm_blocks, 256, 0, stream>>>(
        out, Wt3, as3, ad3, hbuf, a_s, a_d, n);
    agg_kernel<1, false, float><<<agg_blocks, 256, 0, stream>>>(
        hbuf, a_s, a_d, row_start, edge_src, b3, out, n);
  }
}